// Round 6
// baseline (166.648 us; speedup 1.0000x reference)
//
#include <hip/hip_runtime.h>

// SparsityLoss: out = THETA * sum(where(valid, masks, 0)) / (I*(J-1)*K)
// I=128, J=49, K=4096 -> n = 25,690,112 elements.
// masks fp32 (102.8 MB) + valid int32 (102.8 MB) = 205.6 MB irreducible read.
// Round-5 evidence: cold (HBM) and warm (L3) passes run at the same ~5.7 TB/s
// -> CU-side streaming-read ceiling, not source-tier BW. Partial kernel is
// within ~5% of roofline; remaining cost is the finalize dispatch. This round:
// fuse finalize via last-block pattern (counter in ws, zeroed by an 8-B
// memsetAsync each launch -- ws is not re-poisoned between replays and
// self-reset breaks on the first post-poison replay).

static constexpr double kTheta = 0.0001;
static constexpr int kI = 128;
static constexpr int kJ = 49;
static constexpr int kK = 4096;
static constexpr int kBlocks = 2048;     // 8 blocks/CU * 256 CUs
static constexpr int kBlockSize = 256;
static constexpr int kUnroll = 6;

typedef float f32x4 __attribute__((ext_vector_type(4)));
typedef int i32x4 __attribute__((ext_vector_type(4)));

__global__ __launch_bounds__(kBlockSize) void sparsity_fused_kernel(
    const f32x4* __restrict__ masks4,
    const i32x4* __restrict__ valid4,
    double* __restrict__ block_sums,
    unsigned int* __restrict__ counter,   // zeroed by memsetAsync each launch
    int n4,
    const float* __restrict__ masks_tail,
    const int* __restrict__ valid_tail,
    int n_tail,
    float* __restrict__ out) {
    const int tid = blockIdx.x * blockDim.x + threadIdx.x;
    const int stride = gridDim.x * blockDim.x;

    double local = 0.0;
    int i = tid;
    // 6-wide unrolled grid-stride loop (12 x 16B loads issued per iter),
    // compile-time indices only.
    for (; i + (kUnroll - 1) * stride < n4; i += kUnroll * stride) {
        f32x4 m[kUnroll];
        i32x4 v[kUnroll];
#pragma unroll
        for (int k = 0; k < kUnroll; ++k) m[k] = masks4[i + k * stride];
#pragma unroll
        for (int k = 0; k < kUnroll; ++k) v[k] = valid4[i + k * stride];
        double part = 0.0;
#pragma unroll
        for (int k = 0; k < kUnroll; ++k) {
            float sk = (v[k].x ? m[k].x : 0.0f) + (v[k].y ? m[k].y : 0.0f) +
                       (v[k].z ? m[k].z : 0.0f) + (v[k].w ? m[k].w : 0.0f);
            part += (double)sk;
        }
        local += part;
    }
    for (; i < n4; i += stride) {
        f32x4 m = masks4[i];
        i32x4 v = valid4[i];
        float sk = (v.x ? m.x : 0.0f) + (v.y ? m.y : 0.0f) +
                   (v.z ? m.z : 0.0f) + (v.w ? m.w : 0.0f);
        local += (double)sk;
    }
    // Scalar tail (n % 4): empty for n = 25,690,112.
    if (blockIdx.x == 0 && threadIdx.x == 0) {
        for (int t = 0; t < n_tail; ++t) {
            if (valid_tail[t]) local += (double)masks_tail[t];
        }
    }

    // Wave-64 shuffle reduction, then cross-wave via LDS.
    for (int off = 32; off > 0; off >>= 1) {
        local += __shfl_down(local, off, 64);
    }
    __shared__ double wave_sums[kBlockSize / 64];
    __shared__ int is_last;
    const int lane = threadIdx.x & 63;
    const int wid = threadIdx.x >> 6;
    if (lane == 0) wave_sums[wid] = local;
    __syncthreads();

    if (threadIdx.x == 0) {
        double s = wave_sums[0] + wave_sums[1] + wave_sums[2] + wave_sums[3];
        block_sums[blockIdx.x] = s;          // plain store
        __threadfence();                      // release: make store agent-visible
        unsigned int old = __hip_atomic_fetch_add(
            counter, 1u, __ATOMIC_ACQ_REL, __HIP_MEMORY_SCOPE_AGENT);
        is_last = (old == (unsigned int)(gridDim.x - 1)) ? 1 : 0;
    }
    __syncthreads();

    // Last-finishing block reduces all partials and writes the output.
    if (is_last) {
        __threadfence();  // acquire side: invalidate local caches before reads
        double fin = 0.0;
        for (int b = threadIdx.x; b < kBlocks; b += kBlockSize) {
            fin += block_sums[b];
        }
        for (int off = 32; off > 0; off >>= 1) {
            fin += __shfl_down(fin, off, 64);
        }
        __syncthreads();   // wave_sums reuse safety
        if (lane == 0) wave_sums[wid] = fin;
        __syncthreads();
        if (threadIdx.x == 0) {
            double s = wave_sums[0] + wave_sums[1] + wave_sums[2] + wave_sums[3];
            const double denom = (double)kI * (double)(kJ - 1) * (double)kK;
            out[0] = (float)(kTheta * s / denom);
        }
    }
}

extern "C" void kernel_launch(void* const* d_in, const int* in_sizes, int n_in,
                              void* d_out, int out_size, void* d_ws, size_t ws_size,
                              hipStream_t stream) {
    const float* masks = (const float*)d_in[0];
    const int* valid = (const int*)d_in[1];
    const int n = in_sizes[0];

    const int n4 = n / 4;
    const int n_tail = n - n4 * 4;

    // ws layout: [0,64): counter (+padding), [64, 64+kBlocks*8): block_sums
    unsigned int* counter = (unsigned int*)d_ws;
    double* block_sums = (double*)((char*)d_ws + 64);

    hipMemsetAsync(counter, 0, 16, stream);  // counter must be 0 every launch

    sparsity_fused_kernel<<<kBlocks, kBlockSize, 0, stream>>>(
        (const f32x4*)masks, (const i32x4*)valid, block_sums, counter, n4,
        masks + n4 * 4, valid + n4 * 4, n_tail, (float*)d_out);
}

// Round 7
// 39.502 us; speedup vs baseline: 4.2187x; 4.2187x over previous
//
#include <hip/hip_runtime.h>

// SparsityLoss: out = THETA * sum(where(valid, masks, 0)) / (I*(J-1)*K)
// I=128, J=49, K=4096 -> n = 25,690,112 elements.
// masks fp32 (102.8 MB) + valid int32 (102.8 MB) = 205.6 MB irreducible read.
//
// Round-6 post-mortem: last-block fusion with agent-scope ACQ_REL atomics was
// a 4x REGRESSION (40 -> 167 us): every block-retirement forced a per-XCD L2
// writeback/invalidate (~256 per XCD), quiescing the streaming pipeline. The
// kernel boundary provides cross-block visibility once, for free. Two-kernel
// structure restored.
//
// Round-5 evidence: cold(HBM) == warm(L3) at ~5.7 TB/s -> CU-side read ceiling.
// This round: perfect work balance. n4 = 6,422,528 = 1792 blocks x 256 thr x
// 14 groups exactly (was 12.25 -> quarter-pass tail with 75% lanes idle).

static constexpr double kTheta = 0.0001;
static constexpr int kI = 128;
static constexpr int kJ = 49;
static constexpr int kK = 4096;
static constexpr int kBlocks = 1792;     // 7 blocks/CU * 256 CUs; 14 groups/thread exact
static constexpr int kBlockSize = 256;
static constexpr int kUnroll = 7;        // 2 passes of 7 -> 14 groups, zero remainder

typedef float f32x4 __attribute__((ext_vector_type(4)));
typedef int i32x4 __attribute__((ext_vector_type(4)));

__global__ __launch_bounds__(kBlockSize) void sparsity_partial_kernel(
    const f32x4* __restrict__ masks4,
    const i32x4* __restrict__ valid4,
    double* __restrict__ block_sums,
    int n4,
    const float* __restrict__ masks_tail,
    const int* __restrict__ valid_tail,
    int n_tail) {
    const int tid = blockIdx.x * blockDim.x + threadIdx.x;
    const int stride = gridDim.x * blockDim.x;

    double local = 0.0;
    int i = tid;
    // 7-wide unrolled grid-stride loop (14 x 16B loads per pass). For this
    // problem size each thread runs exactly 2 passes; remainder loops are
    // compiled but execute zero iterations.
    for (; i + (kUnroll - 1) * stride < n4; i += kUnroll * stride) {
        f32x4 m[kUnroll];
        i32x4 v[kUnroll];
#pragma unroll
        for (int k = 0; k < kUnroll; ++k) m[k] = masks4[i + k * stride];
#pragma unroll
        for (int k = 0; k < kUnroll; ++k) v[k] = valid4[i + k * stride];
        double part = 0.0;
#pragma unroll
        for (int k = 0; k < kUnroll; ++k) {
            float sk = (v[k].x ? m[k].x : 0.0f) + (v[k].y ? m[k].y : 0.0f) +
                       (v[k].z ? m[k].z : 0.0f) + (v[k].w ? m[k].w : 0.0f);
            part += (double)sk;
        }
        local += part;
    }
    for (; i < n4; i += stride) {
        f32x4 m = masks4[i];
        i32x4 v = valid4[i];
        float sk = (v.x ? m.x : 0.0f) + (v.y ? m.y : 0.0f) +
                   (v.z ? m.z : 0.0f) + (v.w ? m.w : 0.0f);
        local += (double)sk;
    }
    // Scalar tail (n % 4): empty for n = 25,690,112.
    if (blockIdx.x == 0 && threadIdx.x == 0) {
        for (int t = 0; t < n_tail; ++t) {
            if (valid_tail[t]) local += (double)masks_tail[t];
        }
    }

    // Wave-64 shuffle reduction, then cross-wave via LDS.
    for (int off = 32; off > 0; off >>= 1) {
        local += __shfl_down(local, off, 64);
    }
    __shared__ double wave_sums[kBlockSize / 64];
    const int lane = threadIdx.x & 63;
    const int wid = threadIdx.x >> 6;
    if (lane == 0) wave_sums[wid] = local;
    __syncthreads();
    if (threadIdx.x == 0) {
        double s = wave_sums[0] + wave_sums[1] + wave_sums[2] + wave_sums[3];
        block_sums[blockIdx.x] = s;   // plain store; kernel boundary publishes it
    }
}

__global__ __launch_bounds__(kBlockSize) void sparsity_finalize_kernel(
    const double* __restrict__ block_sums, int nblocks,
    float* __restrict__ out) {
    double local = 0.0;
    for (int i = threadIdx.x; i < nblocks; i += kBlockSize) {
        local += block_sums[i];
    }
    for (int off = 32; off > 0; off >>= 1) {
        local += __shfl_down(local, off, 64);
    }
    __shared__ double wave_sums[kBlockSize / 64];
    const int lane = threadIdx.x & 63;
    const int wid = threadIdx.x >> 6;
    if (lane == 0) wave_sums[wid] = local;
    __syncthreads();
    if (threadIdx.x == 0) {
        double s = wave_sums[0] + wave_sums[1] + wave_sums[2] + wave_sums[3];
        const double denom = (double)kI * (double)(kJ - 1) * (double)kK;
        out[0] = (float)(kTheta * s / denom);
    }
}

extern "C" void kernel_launch(void* const* d_in, const int* in_sizes, int n_in,
                              void* d_out, int out_size, void* d_ws, size_t ws_size,
                              hipStream_t stream) {
    const float* masks = (const float*)d_in[0];
    const int* valid = (const int*)d_in[1];
    const int n = in_sizes[0];

    const int n4 = n / 4;
    const int n_tail = n - n4 * 4;

    double* block_sums = (double*)d_ws;  // kBlocks doubles = 14 KB scratch

    sparsity_partial_kernel<<<kBlocks, kBlockSize, 0, stream>>>(
        (const f32x4*)masks, (const i32x4*)valid, block_sums, n4,
        masks + n4 * 4, valid + n4 * 4, n_tail);

    sparsity_finalize_kernel<<<1, kBlockSize, 0, stream>>>(
        block_sums, kBlocks, (float*)d_out);
}